// Round 2
// baseline (48248.752 us; speedup 1.0000x reference)
//
#include <hip/hip_runtime.h>
#include <math.h>

// Problem constants
#define B    64
#define C    128
#define H    32
#define W    32
#define HW   1024
#define OUTC 640
#define NSKIP (B*C*HW)       // 8388608

typedef __attribute__((ext_vector_type(8))) short short8;   // bf16x8 MFMA operand (4 VGPR)
typedef __attribute__((ext_vector_type(4))) float f32x4;    // MFMA accum

// ws layout (floats)
#define ALPHA_OFF 0
#define S0_OFF    64
#define S1_OFF    (S0_OFF + NSKIP)
#define PK_FOFF   (S1_OFF + NSKIP)    // packed bf16 weights start here (as ushort)
// PK: 16 (o,d) x 4 ch x 9 t x 8 mt x 512 lanes*j  bf16 elems = 2359296 (4.72 MB)
#define PK_ELEMS  2359296

__device__ __forceinline__ unsigned short f2bf(float f) {
  unsigned u = __float_as_uint(f);
  unsigned r = (u + 0x7fffu + ((u >> 16) & 1u)) >> 16;
  return (unsigned short)r;
}

// ---------------------------------------------------------------------------
// Prep: softmax(alphas) -> ws[0..40); pack alpha-scaled bf16 weights into
// MFMA A-fragment order: PK[(((o*2+d)*4+ch)*9+t)*4096 + mt*512 + lane*8 + j]
//   co = mt*16 + (lane&15),  ci = ch*32 + (lane>>4)*8 + j
// ---------------------------------------------------------------------------
__global__ __launch_bounds__(256) void prep_kernel(
    const float* __restrict__ alphas, const float* __restrict__ w3,
    const float* __restrict__ wd3, float* __restrict__ ws) {
  __shared__ float as[40];
  int tid = threadIdx.x;
  if (tid < 8) {
    float v[5]; float m = -1e30f;
    for (int j = 0; j < 5; j++) { v[j] = alphas[tid * 5 + j]; m = fmaxf(m, v[j]); }
    float s = 0.f;
    for (int j = 0; j < 5; j++) { v[j] = __expf(v[j] - m); s += v[j]; }
    float inv = 1.f / s;
    for (int j = 0; j < 5; j++) as[tid * 5 + j] = v[j] * inv;
  }
  __syncthreads();
  if (blockIdx.x == 0 && tid < 40) ws[ALPHA_OFF + tid] = as[tid];

  unsigned short* pk = (unsigned short*)(ws + PK_FOFF);
  int stride = gridDim.x * blockDim.x;
  for (int idx = blockIdx.x * 256 + tid; idx < PK_ELEMS; idx += stride) {
    int j    = idx & 7;
    int lane = (idx >> 3) & 63;
    int mt   = (idx >> 9) & 7;
    int rest = idx >> 12;          // g*9 + t,  g = ((o*2+d)*4+ch)
    int t  = rest % 9;
    int g  = rest / 9;
    int ch = g & 3;
    int d  = (g >> 2) & 1;
    int o  = g >> 3;
    int co = mt * 16 + (lane & 15);
    int ci = ch * 32 + (lane >> 4) * 8 + j;
    const float* src = d ? wd3 : w3;
    float a = as[o * 5 + 1 + d];
    float val = src[((o * C + co) * C + ci) * 9 + t] * a;
    pk[idx] = f2bf(val);
  }
}

// ---------------------------------------------------------------------------
// Preprocess 1x1 convs (fp32, unchanged from round 0 - verified)
// ---------------------------------------------------------------------------
__global__ __launch_bounds__(256) void pre_kernel(
    const float* __restrict__ in0, const float* __restrict__ in1,
    const float* __restrict__ wp0, const float* __restrict__ wp1,
    float* __restrict__ ws) {
  int which = blockIdx.z;
  const float* in = which ? in1 : in0;
  const float* wp = which ? wp1 : wp0;
  float* out = ws + (which ? S1_OFF : S0_OFF);
  int b = blockIdx.x;
  int cg = blockIdx.y;
  int t = threadIdx.x;
  int hw0 = t * 4;

  float4 acc[16];
  #pragma unroll
  for (int k = 0; k < 16; k++) acc[k] = make_float4(0.f, 0.f, 0.f, 0.f);

  const float* ip = in + b * (C * HW) + hw0;
  #pragma unroll 4
  for (int ci = 0; ci < C; ci++) {
    float4 x = *(const float4*)(ip + ci * HW);
    #pragma unroll
    for (int k = 0; k < 16; k++) {
      float wv = wp[(cg * 16 + k) * C + ci];
      acc[k].x += wv * x.x; acc[k].y += wv * x.y;
      acc[k].z += wv * x.z; acc[k].w += wv * x.w;
    }
  }
  #pragma unroll
  for (int k = 0; k < 16; k++)
    *(float4*)(out + b * (C * HW) + (cg * 16 + k) * HW + hw0) = acc[k];
}

// ---------------------------------------------------------------------------
// Pool kernel: writes a0*h + a3*avg3(h) + a4*max3(h) summed over both edge
// inputs into the node's output slot (node kernel then adds the convs).
// grid (64 b, 8 cgroups of 16), block 256.
// ---------------------------------------------------------------------------
__global__ __launch_bounds__(256) void pool_kernel(
    const float* __restrict__ h0, int h0bs,
    const float* __restrict__ h1, int h1bs,
    const float* __restrict__ ws, int o0,
    float* __restrict__ outslot) {
  __shared__ float p[2][34][36];
  int b = blockIdx.x, cg = blockIdx.y, tid = threadIdx.x;

  float a00 = ws[ALPHA_OFF + o0 * 5 + 0];
  float a30 = ws[ALPHA_OFF + o0 * 5 + 3];
  float a40 = ws[ALPHA_OFF + o0 * 5 + 4];
  float a01 = ws[ALPHA_OFF + (o0 + 1) * 5 + 0];
  float a31 = ws[ALPHA_OFF + (o0 + 1) * 5 + 3];
  float a41 = ws[ALPHA_OFF + (o0 + 1) * 5 + 4];

  const float* hb[2] = { h0 + b * h0bs, h1 + b * h1bs };
  int y = tid >> 3;
  int x0 = (tid & 7) * 4;

  for (int cc = 0; cc < 16; cc++) {
    int c = cg * 16 + cc;
    __syncthreads();
    for (int j = tid; j < 2 * 34 * 36; j += 256) {
      int i = j / (34 * 36);
      int rem = j - i * (34 * 36);
      int r = rem / 36, col = rem - r * 36;
      int yy = r - 1, xx = col - 1;
      bool v = (yy >= 0) & (yy < H) & (xx >= 0) & (xx < W);
      p[i][r][col] = v ? hb[i][c * HW + yy * W + xx] : 0.f;
    }
    __syncthreads();
    #pragma unroll
    for (int k = 0; k < 4; k++) {
      int x = x0 + k;
      float val = 0.f;
      #pragma unroll
      for (int i = 0; i < 2; i++) {
        float cen = p[i][y + 1][x + 1];
        float s9 = 0.f;
        float mx = cen;
        #pragma unroll
        for (int dy = -1; dy <= 1; dy++)
          #pragma unroll
          for (int dx = -1; dx <= 1; dx++) {
            float pv = p[i][y + 1 + dy][x + 1 + dx];
            s9 += pv;
            int yy = y + dy, xx = x + dx;
            if (yy >= 0 && yy < H && xx >= 0 && xx < W) mx = fmaxf(mx, pv);
          }
        float A0 = i ? a01 : a00, A3 = i ? a31 : a30, A4 = i ? a41 : a40;
        val += A0 * cen + A3 * (s9 * (1.f / 9.f)) + A4 * mx;
      }
      outslot[b * (OUTC * HW) + c * HW + y * W + x] = val;
    }
  }
}

// ---------------------------------------------------------------------------
// Node MFMA kernel: adds the 4 convs (2 edges x {dil1, dil2}) via bf16 MFMA
// implicit GEMM.  grid (64 b, 8 rowgroups), 256 threads = 4 waves.
// Block tile: M=128 co x N=128 (4 rows x 32 cols).  Wave: 4 Mtiles x 4 Ntiles.
// ---------------------------------------------------------------------------
__global__ __launch_bounds__(256, 2) void node_kernel(
    const float* __restrict__ h0, int h0bs,
    const float* __restrict__ h1, int h1bs,
    const float* __restrict__ ws, int o0,
    float* __restrict__ outslot) {
  // LDS: [in(2)][q(4)][r(8)][c(36)][ci8] bf16 => 18432 ushorts = 36 KB
  __shared__ unsigned short lds[2 * 4 * 8 * 36 * 8];

  int b = blockIdx.x, rg = blockIdx.y;
  int tid = threadIdx.x;
  int lane = tid & 63;
  int wv = tid >> 6;
  int wm = wv & 1;            // co half
  int wn = wv >> 1;           // row pair (rows 2*wn, 2*wn+1 of the block's 4)
  int quad = lane >> 4;
  int n16 = lane & 15;

  const unsigned short* pk = (const unsigned short*)(ws + PK_FOFF);
  const float* h0b = h0 + b * h0bs;
  const float* h1b = h1 + b * h1bs;

  // staging thread map
  int sr = tid >> 5;          // 0..7 (staged row)
  int sc = tid & 31;          // x = sc
  int sy = rg * 4 - 2 + sr;
  bool yv = (sy >= 0) & (sy < H);
  int syc = yv ? sy : 0;

  // one-time halo-column zero (cols 0,1,34,35 are always zero-padding)
  {
    int i = tid >> 7, q = (tid >> 5) & 3, r = (tid >> 2) & 7, hc = tid & 3;
    int c = (hc < 2) ? hc : hc + 32;
    short8 z = {0, 0, 0, 0, 0, 0, 0, 0};
    *(short8*)&lds[((i * 4 + q) * 8 + r) * 288 + c * 8] = z;
  }

  f32x4 acc[4][4];
  #pragma unroll
  for (int mt = 0; mt < 4; mt++)
    #pragma unroll
    for (int nt = 0; nt < 4; nt++) acc[mt][nt] = (f32x4){0.f, 0.f, 0.f, 0.f};

  short8 Af[2][4], Bf[2][4];

  // fragment loader for flattened combo cc in [0,36): i = cc/18, d, t
  auto load_frags = [&](int cc, int ch, short8* A, short8* Bv) {
    int i = (cc >= 18) ? 1 : 0;
    int rem = cc - i * 18;
    int d = (rem >= 9) ? 1 : 0;
    int t = rem - d * 9;
    int ky = t / 3, kx = t - ky * 3;
    // A fragments (global, pre-packed)
    const unsigned short* pa = pk +
        (size_t)((((o0 + i) * 2 + d) * 4 + ch) * 9 + t) * 4096 + (wm * 4) * 512 + lane * 8;
    #pragma unroll
    for (int mt = 0; mt < 4; mt++) A[mt] = *(const short8*)(pa + mt * 512);
    // B fragments (LDS)
    int dd = d + 1;           // dilation value
    int rbase = 2 + 2 * wn + dd * (ky - 1);
    int cbase = 2 + dd * (kx - 1) + n16;
    const unsigned short* pb = lds + i * 9216 + quad * 2304 + rbase * 288 + cbase * 8;
    #pragma unroll
    for (int nt = 0; nt < 4; nt++)
      Bv[nt] = *(const short8*)(pb + (nt >> 1) * 288 + (nt & 1) * 128);
  };

  for (int ch = 0; ch < 4; ch++) {
    __syncthreads();
    // ---- stage 32 ci (4 octets) x 8 rows x 32 main cols, both inputs ----
    int ci0 = ch * 32;
    #pragma unroll
    for (int i = 0; i < 2; i++) {
      const float* src = (i ? h1b : h0b) + (size_t)ci0 * HW + syc * W + sc;
      #pragma unroll
      for (int q = 0; q < 4; q++) {
        short8 v;
        if (yv) {
          #pragma unroll
          for (int e = 0; e < 8; e++) v[e] = (short)f2bf(src[(q * 8 + e) * HW]);
        } else {
          #pragma unroll
          for (int e = 0; e < 8; e++) v[e] = 0;
        }
        *(short8*)&lds[((i * 4 + q) * 8 + sr) * 288 + (sc + 2) * 8] = v;
      }
    }
    __syncthreads();

    // ---- 36 combos, 1-deep software pipeline ----
    load_frags(0, ch, Af[0], Bf[0]);
    for (int cc = 0; cc < 36; cc++) {
      int cur = cc & 1;
      if (cc < 35) load_frags(cc + 1, ch, Af[cur ^ 1], Bf[cur ^ 1]);
      #pragma unroll
      for (int mt = 0; mt < 4; mt++)
        #pragma unroll
        for (int nt = 0; nt < 4; nt++)
          acc[mt][nt] = __builtin_amdgcn_mfma_f32_16x16x32_bf16(
              Af[cur][mt], Bf[cur][nt], acc[mt][nt], 0, 0, 0);
    }
  }

  // ---- epilogue: add pool partial (already in outslot), write fp32 ----
  float* ob = outslot + (size_t)b * (OUTC * HW);
  #pragma unroll
  for (int mt = 0; mt < 4; mt++) {
    #pragma unroll
    for (int nt = 0; nt < 4; nt++) {
      int row_local = 2 * wn + (nt >> 1);
      int x = (nt & 1) * 16 + n16;
      int yy = rg * 4 + row_local;
      #pragma unroll
      for (int reg = 0; reg < 4; reg++) {
        int co = wm * 64 + mt * 16 + quad * 4 + reg;
        float* op = ob + co * HW + yy * W + x;
        *op = *op + acc[mt][nt][reg];
      }
    }
  }
}

// ---------------------------------------------------------------------------
// skip_input -> out channels [512,640) and second tuple output
// ---------------------------------------------------------------------------
__global__ __launch_bounds__(256) void skip_kernel(
    const float* __restrict__ skip, float* __restrict__ dout) {
  int i = blockIdx.x * 256 + threadIdx.x;
  if (i < NSKIP / 4) {
    float4 v = ((const float4*)skip)[i];
    int e = i * 4;
    int bb = e >> 17;
    int rem = e & (C * HW - 1);
    *(float4*)(dout + bb * (OUTC * HW) + 512 * HW + rem) = v;
    *(float4*)(dout + (size_t)B * (OUTC * HW) + e) = v;
  }
}

// ---------------------------------------------------------------------------
extern "C" void kernel_launch(void* const* d_in, const int* in_sizes, int n_in,
                              void* d_out, int out_size, void* d_ws, size_t ws_size,
                              hipStream_t stream) {
  const float* input0 = (const float*)d_in[0];
  const float* input1 = (const float*)d_in[1];
  const float* skip   = (const float*)d_in[2];
  const float* wpre0  = (const float*)d_in[3];
  const float* wpre1  = (const float*)d_in[4];
  const float* wconv3 = (const float*)d_in[5];
  const float* wdil3  = (const float*)d_in[6];
  const float* alphas = (const float*)d_in[7];
  float* out = (float*)d_out;
  float* ws  = (float*)d_ws;

  prep_kernel<<<1024, 256, 0, stream>>>(alphas, wconv3, wdil3, ws);
  pre_kernel<<<dim3(B, 8, 2), 256, 0, stream>>>(input0, input1, wpre0, wpre1, ws);

  const float* s0 = ws + S0_OFF;
  const float* s1 = ws + S1_OFF;
  const int wsb = C * HW;
  const int ob  = OUTC * HW;
  float* s2 = out + 0 * C * HW;
  float* s3 = out + 1 * C * HW;
  float* s4 = out + 2 * C * HW;
  float* s5 = out + 3 * C * HW;

  pool_kernel<<<dim3(B, 8), 256, 0, stream>>>(s0, wsb, s1, wsb, ws, 0, s2);
  node_kernel<<<dim3(B, 8), 256, 0, stream>>>(s0, wsb, s1, wsb, ws, 0, s2);

  pool_kernel<<<dim3(B, 8), 256, 0, stream>>>(s1, wsb, s2, ob, ws, 2, s3);
  node_kernel<<<dim3(B, 8), 256, 0, stream>>>(s1, wsb, s2, ob, ws, 2, s3);

  pool_kernel<<<dim3(B, 8), 256, 0, stream>>>(s2, ob, s3, ob, ws, 4, s4);
  node_kernel<<<dim3(B, 8), 256, 0, stream>>>(s2, ob, s3, ob, ws, 4, s4);

  pool_kernel<<<dim3(B, 8), 256, 0, stream>>>(s3, ob, s4, ob, ws, 6, s5);
  node_kernel<<<dim3(B, 8), 256, 0, stream>>>(s3, ob, s4, ob, ws, 6, s5);

  skip_kernel<<<(NSKIP / 4 + 255) / 256, 256, 0, stream>>>(skip, out);
}